// Round 1
// baseline (904.102 us; speedup 1.0000x reference)
//
#include <hip/hip_runtime.h>
#include <math.h>

#define B_   16
#define LQ_  2048
#define LK_  2048
#define D_   128
#define TQ_  64
#define TK_  64
#define NT_  256
#define LN_EPS 1e-5f

// XOR-swizzled LDS index for [rows][128] fp32 tiles, float4-chunk granularity.
// Keeps 16B alignment for ds_read_b128 while spreading row-major column
// accesses across banks (<=2 addresses per bank -> free, m136).
__device__ __forceinline__ int swz(int row, int d) {
  int ch = d >> 2;
  return row * 128 + (((ch ^ (row & 31)) << 2) | (d & 3));
}
// Ps tile [64][64]
__device__ __forceinline__ int swzP(int row, int c) {
  int ch = c >> 2;
  return row * 64 + (((ch ^ (row & 15)) << 2) | (c & 3));
}

__global__ __launch_bounds__(NT_) void attn_ln_kernel(
    const float* __restrict__ qg, const float* __restrict__ kg,
    const float* __restrict__ vg, const float* __restrict__ maskg,
    const float* __restrict__ gammag, const float* __restrict__ betag,
    float* __restrict__ outg)
{
  __shared__ float Qs[TQ_ * D_];
  __shared__ float Ks[TK_ * D_];
  __shared__ float Vs[TK_ * D_];
  __shared__ float Ps[TQ_ * TK_];

  const int tid = threadIdx.x;
  const int tx = tid & 15;        // 0..15  (S cols tx*4+j, O cols tx*8+cc)
  const int ty = tid >> 4;        // 0..15  (rows ty*4+i)
  const int b  = blockIdx.y;
  const int q0 = blockIdx.x * TQ_;

  // ---- stage Q tile (once) ----
  {
    const float* g = qg + ((size_t)b * LQ_ + q0) * D_;
    const int ch = tid & 31;      // float4 chunk 0..31
    const int r0 = tid >> 5;      // 0..7
#pragma unroll
    for (int rr = 0; rr < TQ_; rr += 8) {
      const int row = r0 + rr;
      float4 val = *(const float4*)(g + row * D_ + (ch << 2));
      *(float4*)(&Qs[swz(row, ch << 2)]) = val;
    }
  }

  // gamma/beta for my 8 output columns
  float gam[8], bet[8];
  {
    float4 g0 = *(const float4*)(gammag + tx * 8);
    float4 g1 = *(const float4*)(gammag + tx * 8 + 4);
    float4 b0 = *(const float4*)(betag + tx * 8);
    float4 b1 = *(const float4*)(betag + tx * 8 + 4);
    gam[0]=g0.x; gam[1]=g0.y; gam[2]=g0.z; gam[3]=g0.w;
    gam[4]=g1.x; gam[5]=g1.y; gam[6]=g1.z; gam[7]=g1.w;
    bet[0]=b0.x; bet[1]=b0.y; bet[2]=b0.z; bet[3]=b0.w;
    bet[4]=b1.x; bet[5]=b1.y; bet[6]=b1.z; bet[7]=b1.w;
  }

  float m_i[4], l_i[4];
  float o[4][8];
#pragma unroll
  for (int i = 0; i < 4; i++) {
    m_i[i] = -INFINITY; l_i[i] = 0.f;
#pragma unroll
    for (int c = 0; c < 8; c++) o[i][c] = 0.f;
  }

  const int rbase[4] = { ty*4+0, ty*4+1, ty*4+2, ty*4+3 };

  for (int k0 = 0; k0 < LK_; k0 += TK_) {
    __syncthreads();   // previous PV done with Ks/Vs
    // ---- stage K,V tiles ----
    {
      const float* gk = kg + ((size_t)b * LK_ + k0) * D_;
      const float* gv = vg + ((size_t)b * LK_ + k0) * D_;
      const int ch = tid & 31;
      const int r0 = tid >> 5;
#pragma unroll
      for (int rr = 0; rr < TK_; rr += 8) {
        const int row = r0 + rr;
        float4 kv_ = *(const float4*)(gk + row * D_ + (ch << 2));
        float4 vv_ = *(const float4*)(gv + row * D_ + (ch << 2));
        *(float4*)(&Ks[swz(row, ch << 2)]) = kv_;
        *(float4*)(&Vs[swz(row, ch << 2)]) = vv_;
      }
    }
    __syncthreads();

    // ---- S = Q K^T, 4x4 per thread ----
    float acc[4][4];
#pragma unroll
    for (int i = 0; i < 4; i++)
#pragma unroll
      for (int j = 0; j < 4; j++) acc[i][j] = 0.f;

#pragma unroll 8
    for (int d = 0; d < D_; d += 4) {
      float4 qv[4], kv[4];
#pragma unroll
      for (int i = 0; i < 4; i++) qv[i] = *(const float4*)(&Qs[swz(rbase[i], d)]);
#pragma unroll
      for (int j = 0; j < 4; j++) kv[j] = *(const float4*)(&Ks[swz(tx*4 + j, d)]);
#pragma unroll
      for (int i = 0; i < 4; i++)
#pragma unroll
        for (int j = 0; j < 4; j++) {
          acc[i][j] += qv[i].x * kv[j].x;
          acc[i][j] += qv[i].y * kv[j].y;
          acc[i][j] += qv[i].z * kv[j].z;
          acc[i][j] += qv[i].w * kv[j].w;
        }
    }

    // ---- + mask ----
#pragma unroll
    for (int i = 0; i < 4; i++) {
      const float* mrow = maskg + (size_t)(q0 + rbase[i]) * LK_ + k0 + tx * 4;
      float4 mv = *(const float4*)mrow;
      acc[i][0] += mv.x; acc[i][1] += mv.y; acc[i][2] += mv.z; acc[i][3] += mv.w;
    }

    // ---- online softmax (rows live in 16-lane groups of one wave) ----
#pragma unroll
    for (int i = 0; i < 4; i++) {
      float mx = fmaxf(fmaxf(acc[i][0], acc[i][1]), fmaxf(acc[i][2], acc[i][3]));
#pragma unroll
      for (int m = 1; m <= 8; m <<= 1) mx = fmaxf(mx, __shfl_xor(mx, m, 64));
      float m_new = fmaxf(m_i[i], mx);
      float alpha = __expf(m_i[i] - m_new);     // exp(-inf)=0 on first tile
      float rs = 0.f;
#pragma unroll
      for (int j = 0; j < 4; j++) {
        acc[i][j] = __expf(acc[i][j] - m_new);  // p
        rs += acc[i][j];
      }
#pragma unroll
      for (int m = 1; m <= 8; m <<= 1) rs += __shfl_xor(rs, m, 64);
      l_i[i] = l_i[i] * alpha + rs;
      m_i[i] = m_new;
#pragma unroll
      for (int c = 0; c < 8; c++) o[i][c] *= alpha;
      // store P row-chunk to LDS
      float4 pv = make_float4(acc[i][0], acc[i][1], acc[i][2], acc[i][3]);
      *(float4*)(&Ps[swzP(rbase[i], tx * 4)]) = pv;
    }

    __syncthreads();   // safety: Ps visible (also orders vs staging)

    // ---- O += P * V ----
#pragma unroll 4
    for (int kk = 0; kk < TK_; kk += 4) {
      float4 pv[4];
#pragma unroll
      for (int i = 0; i < 4; i++) pv[i] = *(const float4*)(&Ps[swzP(rbase[i], kk)]);
#pragma unroll
      for (int t = 0; t < 4; t++) {
        float4 va = *(const float4*)(&Vs[swz(kk + t, tx * 8)]);
        float4 vb = *(const float4*)(&Vs[swz(kk + t, tx * 8 + 4)]);
        float pw[4];
        pw[0] = (t == 0) ? pv[0].x : (t == 1) ? pv[0].y : (t == 2) ? pv[0].z : pv[0].w;
        pw[1] = (t == 0) ? pv[1].x : (t == 1) ? pv[1].y : (t == 2) ? pv[1].z : pv[1].w;
        pw[2] = (t == 0) ? pv[2].x : (t == 1) ? pv[2].y : (t == 2) ? pv[2].z : pv[2].w;
        pw[3] = (t == 0) ? pv[3].x : (t == 1) ? pv[3].y : (t == 2) ? pv[3].z : pv[3].w;
#pragma unroll
        for (int i = 0; i < 4; i++) {
          o[i][0] += pw[i] * va.x; o[i][1] += pw[i] * va.y;
          o[i][2] += pw[i] * va.z; o[i][3] += pw[i] * va.w;
          o[i][4] += pw[i] * vb.x; o[i][5] += pw[i] * vb.y;
          o[i][6] += pw[i] * vb.z; o[i][7] += pw[i] * vb.w;
        }
      }
    }
  }

  // ---- epilogue: 1/l, LayerNorm over D=128, scale/shift, store ----
#pragma unroll
  for (int i = 0; i < 4; i++) {
    float inv_l = 1.f / l_i[i];
#pragma unroll
    for (int c = 0; c < 8; c++) o[i][c] *= inv_l;

    float s1 = 0.f, s2 = 0.f;
#pragma unroll
    for (int c = 0; c < 8; c++) { s1 += o[i][c]; s2 += o[i][c] * o[i][c]; }
#pragma unroll
    for (int m = 1; m <= 8; m <<= 1) {
      s1 += __shfl_xor(s1, m, 64);
      s2 += __shfl_xor(s2, m, 64);
    }
    const float mean = s1 * (1.f / 128.f);
    const float var  = s2 * (1.f / 128.f) - mean * mean;
    const float rstd = rsqrtf(var + LN_EPS);

    float res[8];
#pragma unroll
    for (int c = 0; c < 8; c++)
      res[c] = (o[i][c] - mean) * rstd * gam[c] + bet[c];

    float* orow = outg + ((size_t)b * LQ_ + q0 + rbase[i]) * D_ + tx * 8;
    *(float4*)(orow)     = make_float4(res[0], res[1], res[2], res[3]);
    *(float4*)(orow + 4) = make_float4(res[4], res[5], res[6], res[7]);
  }
}

extern "C" void kernel_launch(void* const* d_in, const int* in_sizes, int n_in,
                              void* d_out, int out_size, void* d_ws, size_t ws_size,
                              hipStream_t stream) {
  const float* q     = (const float*)d_in[0];
  const float* k     = (const float*)d_in[1];
  const float* v     = (const float*)d_in[2];
  const float* mask  = (const float*)d_in[3];
  const float* gamma = (const float*)d_in[4];
  const float* beta  = (const float*)d_in[5];
  float* out = (float*)d_out;

  dim3 grid(LQ_ / TQ_, B_);
  attn_ln_kernel<<<grid, dim3(NT_), 0, stream>>>(q, k, v, mask, gamma, beta, out);
}

// Round 2
// 367.531 us; speedup vs baseline: 2.4599x; 2.4599x over previous
//
#include <hip/hip_runtime.h>
#include <hip/hip_bf16.h>
#include <math.h>

#define B_   16
#define LQ_  2048
#define LK_  2048
#define D_   128
#define LN_EPS 1e-5f

typedef __attribute__((ext_vector_type(8))) short short8;
typedef __attribute__((ext_vector_type(4))) float f32x4;

union FragU { uint4 u4; short8 s8; unsigned int u[4]; };

__device__ __forceinline__ unsigned int pk_bf16(float a, float b) {
  __hip_bfloat162 h = __float22bfloat162_rn(make_float2(a, b));
  unsigned int u;
  __builtin_memcpy(&u, &h, 4);
  return u;
}
__device__ __forceinline__ float bf_lo(unsigned int u){ unsigned int v = u << 16; float f; __builtin_memcpy(&f, &v, 4); return f; }
__device__ __forceinline__ float bf_hi(unsigned int u){ unsigned int v = u & 0xffff0000u; float f; __builtin_memcpy(&f, &v, 4); return f; }

// K tiles: ushort [64 rows][128 d], 16B-chunk (8 ushort) XOR swizzle by row.
__device__ __forceinline__ int idxK(int row, int d) {
  int ch = d >> 3;
  return row * 128 + ((((ch ^ row) & 15)) << 3) + (d & 7);
}
// V transposed: ushort [128 d][64 kv], 16B-chunk swizzle by f(d)=(d^(d>>2))&7
// (spreads banks for BOTH the kv-contiguous frag reads and the d-varying
//  transpose writes, where d is float4-aligned).
__device__ __forceinline__ int idxV(int d, int kv) {
  int ch = kv >> 3;
  int f  = (d ^ (d >> 2)) & 7;
  return d * 64 + (((ch ^ f) & 7) << 3) + (kv & 7);
}
// P scratch: float [4 waves][16 rows][64 cols], 16B-chunk (4 fp32) swizzle by row.
__device__ __forceinline__ int idxP(int w, int row, int col) {
  int ch = col >> 2;
  return (w * 16 + row) * 64 + (((ch ^ row) & 15) << 2) + (col & 3);
}

__global__ __launch_bounds__(256, 2) void attn_ln_mfma(
    const float* __restrict__ qg, const float* __restrict__ kg,
    const float* __restrict__ vg, const float* __restrict__ maskg,
    const float* __restrict__ gammag, const float* __restrict__ betag,
    float* __restrict__ outg)
{
  __shared__ unsigned short KhS[64 * 128];   // 16 KB
  __shared__ unsigned short KlS[64 * 128];   // 16 KB
  __shared__ unsigned short VtS[128 * 64];   // 16 KB
  __shared__ float          PsS[4 * 16 * 64]; // 16 KB

  const int tid  = threadIdx.x;
  const int w    = tid >> 6;       // wave 0..3
  const int lane = tid & 63;
  const int quad = lane >> 4;      // 0..3
  const int lr   = lane & 15;      // 0..15
  const int b    = blockIdx.y;
  const int q0   = blockIdx.x * 64;
  const int ch   = tid & 31;       // staging: float4 chunk within a 128-elem row
  const int r0   = tid >> 5;       // staging: row base 0..7

  // ---- Q fragments (hi/lo), held in registers for the whole k-loop ----
  short8 qh[4], ql[4];
  {
    const float* qrow = qg + ((size_t)b * LQ_ + q0 + w * 16 + lr) * D_ + quad * 8;
#pragma unroll
    for (int c = 0; c < 4; c++) {
      float4 x = *(const float4*)(qrow + c * 32);
      float4 y = *(const float4*)(qrow + c * 32 + 4);
      FragU H, L;
      H.u[0] = pk_bf16(x.x, x.y); H.u[1] = pk_bf16(x.z, x.w);
      H.u[2] = pk_bf16(y.x, y.y); H.u[3] = pk_bf16(y.z, y.w);
      L.u[0] = pk_bf16(x.x - bf_lo(H.u[0]), x.y - bf_hi(H.u[0]));
      L.u[1] = pk_bf16(x.z - bf_lo(H.u[1]), x.w - bf_hi(H.u[1]));
      L.u[2] = pk_bf16(y.x - bf_lo(H.u[2]), y.y - bf_hi(H.u[2]));
      L.u[3] = pk_bf16(y.z - bf_lo(H.u[3]), y.w - bf_hi(H.u[3]));
      qh[c] = H.s8; ql[c] = L.s8;
    }
  }

  // gamma/beta for my 8 output columns (col = n*16 + lr)
  float gam[8], bet[8];
#pragma unroll
  for (int n = 0; n < 8; n++) {
    gam[n] = gammag[n * 16 + lr];
    bet[n] = betag[n * 16 + lr];
  }

  float m_i[4], l_i[4];
  f32x4 o[8];
  const f32x4 zf = {0.f, 0.f, 0.f, 0.f};
#pragma unroll
  for (int r = 0; r < 4; r++) { m_i[r] = -INFINITY; l_i[r] = 0.f; }
#pragma unroll
  for (int n = 0; n < 8; n++) o[n] = zf;

  for (int k0 = 0; k0 < LK_; k0 += 64) {
    __syncthreads();   // all waves done reading K/V tiles of previous iter

    // ---- stage K (hi/lo bf16) and V (bf16, transposed) ----
    {
      const float* gk = kg + ((size_t)b * LK_ + k0) * D_ + ch * 4;
      const float* gv = vg + ((size_t)b * LK_ + k0) * D_ + ch * 4;
      const int d0 = ch * 4;
#pragma unroll
      for (int rr = 0; rr < 64; rr += 8) {
        const int row = r0 + rr;
        float4 kk = *(const float4*)(gk + row * D_);
        unsigned int h01 = pk_bf16(kk.x, kk.y), h23 = pk_bf16(kk.z, kk.w);
        unsigned int l01 = pk_bf16(kk.x - bf_lo(h01), kk.y - bf_hi(h01));
        unsigned int l23 = pk_bf16(kk.z - bf_lo(h23), kk.w - bf_hi(h23));
        const int ik = idxK(row, d0);
        *(uint2*)&KhS[ik] = make_uint2(h01, h23);
        *(uint2*)&KlS[ik] = make_uint2(l01, l23);

        float4 vv = *(const float4*)(gv + row * D_);
        unsigned int v01 = pk_bf16(vv.x, vv.y), v23 = pk_bf16(vv.z, vv.w);
        VtS[idxV(d0 + 0, row)] = (unsigned short)(v01 & 0xffffu);
        VtS[idxV(d0 + 1, row)] = (unsigned short)(v01 >> 16);
        VtS[idxV(d0 + 2, row)] = (unsigned short)(v23 & 0xffffu);
        VtS[idxV(d0 + 3, row)] = (unsigned short)(v23 >> 16);
      }
    }

    // mask values for this tile (issue early; global, L3-resident)
    float mkv[4][4];
#pragma unroll
    for (int t = 0; t < 4; t++)
#pragma unroll
      for (int reg = 0; reg < 4; reg++)
        mkv[t][reg] = maskg[(size_t)(q0 + w * 16 + quad * 4 + reg) * LK_ + k0 + t * 16 + lr];

    __syncthreads();   // staged tiles visible

    // ---- S = Q K^T via MFMA (hi/lo: qh*kh + ql*kh + qh*kl) ----
    f32x4 sacc[4];
#pragma unroll
    for (int t = 0; t < 4; t++) sacc[t] = zf;
#pragma unroll
    for (int c = 0; c < 4; c++) {
      const int kb = c * 32 + quad * 8;
#pragma unroll
      for (int t = 0; t < 4; t++) {
        FragU kh, kl;
        kh.u4 = *(const uint4*)&KhS[idxK(t * 16 + lr, kb)];
        kl.u4 = *(const uint4*)&KlS[idxK(t * 16 + lr, kb)];
        sacc[t] = __builtin_amdgcn_mfma_f32_16x16x32_bf16(qh[c], kh.s8, sacc[t], 0, 0, 0);
        sacc[t] = __builtin_amdgcn_mfma_f32_16x16x32_bf16(ql[c], kh.s8, sacc[t], 0, 0, 0);
        sacc[t] = __builtin_amdgcn_mfma_f32_16x16x32_bf16(qh[c], kl.s8, sacc[t], 0, 0, 0);
      }
    }

    // ---- + mask, online softmax (per row = quad*4+reg) ----
#pragma unroll
    for (int t = 0; t < 4; t++)
#pragma unroll
      for (int reg = 0; reg < 4; reg++) sacc[t][reg] += mkv[t][reg];

#pragma unroll
    for (int reg = 0; reg < 4; reg++) {
      float mx = fmaxf(fmaxf(sacc[0][reg], sacc[1][reg]),
                       fmaxf(sacc[2][reg], sacc[3][reg]));
#pragma unroll
      for (int m = 1; m <= 8; m <<= 1) mx = fmaxf(mx, __shfl_xor(mx, m, 64));
      const float mnew  = fmaxf(m_i[reg], mx);
      const float alpha = __expf(m_i[reg] - mnew);   // 0 on first tile
      float p[4]; float rs = 0.f;
#pragma unroll
      for (int t = 0; t < 4; t++) { p[t] = __expf(sacc[t][reg] - mnew); rs += p[t]; }
#pragma unroll
      for (int m = 1; m <= 8; m <<= 1) rs += __shfl_xor(rs, m, 64);
      l_i[reg] = l_i[reg] * alpha + rs;
      m_i[reg] = mnew;
#pragma unroll
      for (int n = 0; n < 8; n++) o[n][reg] *= alpha;
      // P to per-wave LDS scratch (C-layout -> A-layout round trip)
#pragma unroll
      for (int t = 0; t < 4; t++)
        PsS[idxP(w, quad * 4 + reg, t * 16 + lr)] = p[t];
    }

    asm volatile("s_waitcnt lgkmcnt(0)" ::: "memory");  // own P writes visible (per-wave region)

    // ---- O += P * V via MFMA ----
#pragma unroll
    for (int s = 0; s < 2; s++) {
      const int kb = s * 32 + quad * 8;
      float4 pa = *(const float4*)&PsS[idxP(w, lr, kb)];
      float4 pb = *(const float4*)&PsS[idxP(w, lr, kb + 4)];
      FragU A;
      A.u[0] = pk_bf16(pa.x, pa.y); A.u[1] = pk_bf16(pa.z, pa.w);
      A.u[2] = pk_bf16(pb.x, pb.y); A.u[3] = pk_bf16(pb.z, pb.w);
#pragma unroll
      for (int n = 0; n < 8; n++) {
        FragU Bv;
        Bv.u4 = *(const uint4*)&VtS[idxV(n * 16 + lr, kb)];
        o[n] = __builtin_amdgcn_mfma_f32_16x16x32_bf16(A.s8, Bv.s8, o[n], 0, 0, 0);
      }
    }
  }

  // ---- epilogue: normalize by l, LayerNorm over D=128, store ----
#pragma unroll
  for (int reg = 0; reg < 4; reg++) {
    const float inv_l = 1.f / l_i[reg];
    float vals[8];
    float s1 = 0.f, s2 = 0.f;
#pragma unroll
    for (int n = 0; n < 8; n++) {
      vals[n] = o[n][reg] * inv_l;
      s1 += vals[n]; s2 += vals[n] * vals[n];
    }
#pragma unroll
    for (int m = 1; m <= 8; m <<= 1) {
      s1 += __shfl_xor(s1, m, 64);
      s2 += __shfl_xor(s2, m, 64);
    }
    const float mean = s1 * (1.f / 128.f);
    const float var  = s2 * (1.f / 128.f) - mean * mean;
    const float rstd = rsqrtf(var + LN_EPS);

    float* op = outg + ((size_t)b * LQ_ + q0 + w * 16 + quad * 4 + reg) * D_ + lr;
#pragma unroll
    for (int n = 0; n < 8; n++)
      op[n * 16] = (vals[n] - mean) * rstd * gam[n] + bet[n];
  }
}

extern "C" void kernel_launch(void* const* d_in, const int* in_sizes, int n_in,
                              void* d_out, int out_size, void* d_ws, size_t ws_size,
                              hipStream_t stream) {
  const float* q     = (const float*)d_in[0];
  const float* k     = (const float*)d_in[1];
  const float* v     = (const float*)d_in[2];
  const float* mask  = (const float*)d_in[3];
  const float* gamma = (const float*)d_in[4];
  const float* beta  = (const float*)d_in[5];
  float* out = (float*)d_out;

  dim3 grid(LQ_ / 64, B_);
  attn_ln_mfma<<<grid, dim3(256), 0, stream>>>(q, k, v, mask, gamma, beta, out);
}

// Round 3
// 231.376 us; speedup vs baseline: 3.9075x; 1.5885x over previous
//
#include <hip/hip_runtime.h>
#include <hip/hip_bf16.h>
#include <math.h>

#define B_   16
#define LQ_  2048
#define LK_  2048
#define D_   128
#define LN_EPS 1e-5f
#define NTILE (LK_ / 64)

typedef __attribute__((ext_vector_type(8))) short short8;
typedef __attribute__((ext_vector_type(4))) float f32x4;

union FragU { uint4 u4; short8 s8; unsigned int u[4]; };

__device__ __forceinline__ unsigned int pk_bf16(float a, float b) {
  __hip_bfloat162 h = __float22bfloat162_rn(make_float2(a, b));
  unsigned int u;
  __builtin_memcpy(&u, &h, 4);
  return u;
}
__device__ __forceinline__ float bf_lo(unsigned int u){ unsigned int v = u << 16; float f; __builtin_memcpy(&f, &v, 4); return f; }
__device__ __forceinline__ float bf_hi(unsigned int u){ unsigned int v = u & 0xffff0000u; float f; __builtin_memcpy(&f, &v, 4); return f; }

// K tiles: ushort [64 rows][128 d], 16B-chunk XOR swizzle by row.
__device__ __forceinline__ int idxK(int row, int d) {
  int ch = d >> 3;
  return row * 128 + ((((ch ^ row) & 15)) << 3) + (d & 7);
}
// V transposed: ushort [128 d][64 kv], swizzle f(d)=(d^(d>>2))&7.
__device__ __forceinline__ int idxV(int d, int kv) {
  int ch = kv >> 3;
  int f  = (d ^ (d >> 2)) & 7;
  return d * 64 + (((ch ^ f) & 7) << 3) + (kv & 7);
}
// P scratch: float [4 waves][16 rows][64 cols], 4-fp32-chunk swizzle by row.
__device__ __forceinline__ int idxP(int w, int row, int col) {
  int ch = col >> 2;
  return (w * 16 + row) * 64 + (((ch ^ row) & 15) << 2) + (col & 3);
}

// LDS-only barrier: drains ds ops, leaves global (vmcnt) loads in flight.
// __syncthreads() would force vmcnt(0) and kill the cross-tile prefetch.
__device__ __forceinline__ void barrier_lds() {
  asm volatile("s_waitcnt lgkmcnt(0)\n\ts_barrier" ::: "memory");
}

__global__ __launch_bounds__(256, 2) void attn_ln_mfma(
    const float* __restrict__ qg, const float* __restrict__ kg,
    const float* __restrict__ vg, const float* __restrict__ maskg,
    const float* __restrict__ gammag, const float* __restrict__ betag,
    float* __restrict__ outg)
{
  __shared__ unsigned short KhS[64 * 128];    // 16 KB
  __shared__ unsigned short KlS[64 * 128];    // 16 KB
  __shared__ unsigned short VtS[128 * 64];    // 16 KB
  __shared__ float          PsS[4 * 16 * 64]; // 16 KB

  const int tid  = threadIdx.x;
  const int w    = tid >> 6;
  const int lane = tid & 63;
  const int quad = lane >> 4;
  const int lr   = lane & 15;
  const int b    = blockIdx.y;
  const int q0   = blockIdx.x * 64;
  const int ch   = tid & 31;      // staging: float4 chunk within a row
  const int r0   = tid >> 5;      // staging: row base 0..7 (rows r0 + 8*i)

  const float* gkbase = kg + ((size_t)b * LK_) * D_ + ch * 4;
  const float* gvbase = vg + ((size_t)b * LK_) * D_ + ch * 4;

  // ---- prefetch tile 0 K/V into registers ----
  float4 kpre[8], vpre[8];
#pragma unroll
  for (int i = 0; i < 8; i++) {
    kpre[i] = *(const float4*)(gkbase + (size_t)(r0 + i * 8) * D_);
    vpre[i] = *(const float4*)(gvbase + (size_t)(r0 + i * 8) * D_);
  }

  // ---- Q fragments (hi/lo), registers for the whole k-loop ----
  short8 qh[4], ql[4];
  {
    const float* qrow = qg + ((size_t)b * LQ_ + q0 + w * 16 + lr) * D_ + quad * 8;
#pragma unroll
    for (int c = 0; c < 4; c++) {
      float4 x = *(const float4*)(qrow + c * 32);
      float4 y = *(const float4*)(qrow + c * 32 + 4);
      FragU H, L;
      H.u[0] = pk_bf16(x.x, x.y); H.u[1] = pk_bf16(x.z, x.w);
      H.u[2] = pk_bf16(y.x, y.y); H.u[3] = pk_bf16(y.z, y.w);
      L.u[0] = pk_bf16(x.x - bf_lo(H.u[0]), x.y - bf_hi(H.u[0]));
      L.u[1] = pk_bf16(x.z - bf_lo(H.u[1]), x.w - bf_hi(H.u[1]));
      L.u[2] = pk_bf16(y.x - bf_lo(H.u[2]), y.y - bf_hi(H.u[2]));
      L.u[3] = pk_bf16(y.z - bf_lo(H.u[3]), y.w - bf_hi(H.u[3]));
      qh[c] = H.s8; ql[c] = L.s8;
    }
  }

  float l_part[4];                 // deferred softmax denominator (per-thread partials)
  f32x4 o[8];
  const f32x4 zf = {0.f, 0.f, 0.f, 0.f};
#pragma unroll
  for (int r = 0; r < 4; r++) l_part[r] = 0.f;
#pragma unroll
  for (int n = 0; n < 8; n++) o[n] = zf;

  for (int kt = 0; kt < NTILE; kt++) {
    const int k0 = kt * 64;
    barrier_lds();   // all waves done reading previous tile's LDS

    // mask loads for THIS tile (issued early; consumed after QK MFMAs)
    float mkv[4][4];
#pragma unroll
    for (int t = 0; t < 4; t++)
#pragma unroll
      for (int reg = 0; reg < 4; reg++)
        mkv[t][reg] = maskg[(size_t)(q0 + w * 16 + quad * 4 + reg) * LK_ + k0 + t * 16 + lr];

    // ---- convert prefetched regs -> LDS (K hi/lo bf16, V bf16 transposed) ----
    {
      const int d0 = ch * 4;
#pragma unroll
      for (int i = 0; i < 8; i++) {
        const int row = r0 + i * 8;
        float4 kk = kpre[i];
        unsigned int h01 = pk_bf16(kk.x, kk.y), h23 = pk_bf16(kk.z, kk.w);
        unsigned int l01 = pk_bf16(kk.x - bf_lo(h01), kk.y - bf_hi(h01));
        unsigned int l23 = pk_bf16(kk.z - bf_lo(h23), kk.w - bf_hi(h23));
        const int ik = idxK(row, d0);
        *(uint2*)&KhS[ik] = make_uint2(h01, h23);
        *(uint2*)&KlS[ik] = make_uint2(l01, l23);

        float4 vv = vpre[i];
        unsigned int v01 = pk_bf16(vv.x, vv.y), v23 = pk_bf16(vv.z, vv.w);
        VtS[idxV(d0 + 0, row)] = (unsigned short)(v01 & 0xffffu);
        VtS[idxV(d0 + 1, row)] = (unsigned short)(v01 >> 16);
        VtS[idxV(d0 + 2, row)] = (unsigned short)(v23 & 0xffffu);
        VtS[idxV(d0 + 3, row)] = (unsigned short)(v23 >> 16);
      }
    }

    // ---- prefetch NEXT tile (stays in flight across the raw barrier) ----
    if (kt + 1 < NTILE) {
      const float* gk = gkbase + (size_t)(k0 + 64) * D_;
      const float* gv = gvbase + (size_t)(k0 + 64) * D_;
#pragma unroll
      for (int i = 0; i < 8; i++) {
        kpre[i] = *(const float4*)(gk + (size_t)(r0 + i * 8) * D_);
        vpre[i] = *(const float4*)(gv + (size_t)(r0 + i * 8) * D_);
      }
    }

    barrier_lds();   // staged tile visible

    // ---- S = Q K^T via MFMA (hi/lo: qh*kh + ql*kh + qh*kl) ----
    f32x4 sacc[4];
#pragma unroll
    for (int t = 0; t < 4; t++) sacc[t] = zf;
#pragma unroll
    for (int c = 0; c < 4; c++) {
      const int kb = c * 32 + quad * 8;
#pragma unroll
      for (int t = 0; t < 4; t++) {
        FragU kh, kl;
        kh.u4 = *(const uint4*)&KhS[idxK(t * 16 + lr, kb)];
        kl.u4 = *(const uint4*)&KlS[idxK(t * 16 + lr, kb)];
        sacc[t] = __builtin_amdgcn_mfma_f32_16x16x32_bf16(qh[c], kh.s8, sacc[t], 0, 0, 0);
        sacc[t] = __builtin_amdgcn_mfma_f32_16x16x32_bf16(ql[c], kh.s8, sacc[t], 0, 0, 0);
        sacc[t] = __builtin_amdgcn_mfma_f32_16x16x32_bf16(qh[c], kl.s8, sacc[t], 0, 0, 0);
      }
    }

    // ---- max-free softmax: p = exp(s + mask); accumulate per-thread l ----
#pragma unroll
    for (int reg = 0; reg < 4; reg++) {
      float p[4];
#pragma unroll
      for (int t = 0; t < 4; t++) p[t] = __expf(sacc[t][reg] + mkv[t][reg]);
      l_part[reg] += (p[0] + p[1]) + (p[2] + p[3]);
#pragma unroll
      for (int t = 0; t < 4; t++)
        PsS[idxP(w, quad * 4 + reg, t * 16 + lr)] = p[t];
    }

    asm volatile("s_waitcnt lgkmcnt(0)" ::: "memory");  // own P writes visible

    // ---- O += P * V via MFMA ----
#pragma unroll
    for (int s = 0; s < 2; s++) {
      const int kb = s * 32 + quad * 8;
      float4 pa = *(const float4*)&PsS[idxP(w, lr, kb)];
      float4 pb = *(const float4*)&PsS[idxP(w, lr, kb + 4)];
      FragU A;
      A.u[0] = pk_bf16(pa.x, pa.y); A.u[1] = pk_bf16(pa.z, pa.w);
      A.u[2] = pk_bf16(pb.x, pb.y); A.u[3] = pk_bf16(pb.z, pb.w);
#pragma unroll
      for (int n = 0; n < 8; n++) {
        FragU Bv;
        Bv.u4 = *(const uint4*)&VtS[idxV(n * 16 + lr, kb)];
        o[n] = __builtin_amdgcn_mfma_f32_16x16x32_bf16(A.s8, Bv.s8, o[n], 0, 0, 0);
      }
    }
  }

  // ---- epilogue: reduce l, normalize, LayerNorm, store ----
  float gam[8], bet[8];
#pragma unroll
  for (int n = 0; n < 8; n++) {
    gam[n] = gammag[n * 16 + lr];
    bet[n] = betag[n * 16 + lr];
  }

#pragma unroll
  for (int reg = 0; reg < 4; reg++) {
    float l = l_part[reg];
#pragma unroll
    for (int m = 1; m <= 8; m <<= 1) l += __shfl_xor(l, m, 64);
    const float inv_l = 1.f / l;

    float vals[8];
    float s1 = 0.f, s2 = 0.f;
#pragma unroll
    for (int n = 0; n < 8; n++) {
      vals[n] = o[n][reg] * inv_l;
      s1 += vals[n]; s2 += vals[n] * vals[n];
    }
#pragma unroll
    for (int m = 1; m <= 8; m <<= 1) {
      s1 += __shfl_xor(s1, m, 64);
      s2 += __shfl_xor(s2, m, 64);
    }
    const float mean = s1 * (1.f / 128.f);
    const float var  = s2 * (1.f / 128.f) - mean * mean;
    const float rstd = rsqrtf(var + LN_EPS);

    float* op = outg + ((size_t)b * LQ_ + q0 + w * 16 + quad * 4 + reg) * D_ + lr;
#pragma unroll
    for (int n = 0; n < 8; n++)
      op[n * 16] = (vals[n] - mean) * rstd * gam[n] + bet[n];
  }
}

extern "C" void kernel_launch(void* const* d_in, const int* in_sizes, int n_in,
                              void* d_out, int out_size, void* d_ws, size_t ws_size,
                              hipStream_t stream) {
  const float* q     = (const float*)d_in[0];
  const float* k     = (const float*)d_in[1];
  const float* v     = (const float*)d_in[2];
  const float* mask  = (const float*)d_in[3];
  const float* gamma = (const float*)d_in[4];
  const float* beta  = (const float*)d_in[5];
  float* out = (float*)d_out;

  dim3 grid(LQ_ / 64, B_);
  attn_ln_mfma<<<grid, dim3(256), 0, stream>>>(q, k, v, mask, gamma, beta, out);
}